// Round 13
// baseline (159.334 us; speedup 1.0000x reference)
//
#include <hip/hip_runtime.h>

#define GRID_H 20
#define GRID_W 80
#define NCH 264
#define K 256
#define NPIX 128   // 16x8 glyph pixels

typedef __attribute__((ext_vector_type(8))) short short8;
typedef __attribute__((ext_vector_type(4))) float f32x4;
typedef __attribute__((ext_vector_type(8))) unsigned short u16x8;

static __device__ __forceinline__ unsigned short f2bf(float f) {
    unsigned int u = __builtin_bit_cast(unsigned int, f);
    u += 0x7FFFu + ((u >> 16) & 1u);   // round-to-nearest-even
    return (unsigned short)(u >> 16);
}

// Swizzled byte offset within a 32KB pixel-half (R9/R12-proven layout):
// 64 rows (local pixel) x 512B (256 bf16 channels), XOR (pl&7)<<4.
static __device__ __forceinline__ int bswz(int pl, int clbyte) {
    return (pl * 512 + clbyte) ^ ((pl & 7) << 4);
}

// Pack cm (f32 [256 ch][128 px]) -> ws: two 32KB pixel-halves whose LINEAR
// byte order equals the main kernel's swizzled LDS layout (R12-proven).
__global__ void prep_kernel(const float* __restrict__ cm,
                            unsigned short* __restrict__ ws) {
    int i = blockIdx.x * 256 + threadIdx.x;   // 0..4095 chunks of 16B
    int p  = i & 127;                         // pixel 0..127
    int c8 = i >> 7;                          // channel-group of 8 (0..31)
    int hf = p >> 6, pl = p & 63;
    u16x8 pk;
    #pragma unroll
    for (int j = 0; j < 8; ++j) pk[j] = f2bf(cm[(c8 * 8 + j) * NPIX + p]);
    *reinterpret_cast<u16x8*>((char*)ws + hf * 32768 + bswz(pl, c8 * 16)) = pk;
}

// NOTE: plain 1-arg launch_bounds only. The 2-arg form (min waves/EU)
// miscompiled MFMA accumulation in R2/R3/R7.
template <bool USE_WS>
__global__ __launch_bounds__(320) void ansi_kernel(
        const float* __restrict__ data,
        const float* __restrict__ cm,
        const unsigned short* __restrict__ ws,
        float* __restrict__ out) {
    // ONLY LDS: one 32 KB pixel-half of cm (now the A operand). 5 blocks/CU.
    __shared__ alignas(16) unsigned char ldsB[32768];

    const int blk = blockIdx.x;
    const int b = blk / GRID_H;
    const int h = blk % GRID_H;
    const float* dbase = data + (size_t)(b * GRID_H + h) * GRID_W * NCH;
    const int t = threadIdx.x;
    const int wave = t >> 6;
    const int lane = t & 63;
    const int lc   = lane & 15;     // this lane's cell within the wave's 16
    const int g    = lane >> 4;     // k-group / D-row group
    const int cell0 = wave * 16;

    // ---- per-lane fg/bg for OWN cell (redundant x4 across g, L1-absorbed) ----
    const float* q = dbase + (size_t)(cell0 + lc) * NCH + 256;
    float4 fa = *reinterpret_cast<const float4*>(q);      // fg_bold, fg.rgb
    float4 fc = *reinterpret_cast<const float4*>(q + 4);  // bg_bold, bg.rgb
    float fs = 0.5f * fa.x + 0.5f;
    float bs = 0.5f * fc.x + 0.5f;
    float bg0 = bs * fc.y, bg1 = bs * fc.z, bg2 = bs * fc.w;
    float dv0 = fs * fa.y - bg0, dv1 = fs * fa.z - bg1, dv2 = fs * fa.w - bg2;

    // ---- load + pack B (data, this lane's cell, full K=256): 8 x bf16x8 ----
    const float* brow = dbase + (size_t)(cell0 + lc) * NCH + g * 8;
    short8 bpk[8];
    #pragma unroll
    for (int ks = 0; ks < 8; ++ks) {
        float4 a0 = *reinterpret_cast<const float4*>(brow + ks * 32);
        float4 a1 = *reinterpret_cast<const float4*>(brow + ks * 32 + 4);
        u16x8 ap;
        ap[0] = f2bf(a0.x); ap[1] = f2bf(a0.y); ap[2] = f2bf(a0.z); ap[3] = f2bf(a0.w);
        ap[4] = f2bf(a1.x); ap[5] = f2bf(a1.y); ap[6] = f2bf(a1.z); ap[7] = f2bf(a1.w);
        bpk[ks] = __builtin_bit_cast(short8, ap);
    }

    f32x4 acc[8];
    #pragma unroll
    for (int m = 0; m < 8; ++m) acc[m] = (f32x4){0.f, 0.f, 0.f, 0.f};

    // ---- GEMM over two pixel-halves (pixels are M now); 3 barriers total ----
    #pragma unroll
    for (int half = 0; half < 2; ++half) {
        if (USE_WS) {
            // async byte-copy: ws linear order == swizzled LDS order (R12)
            const char* src = (const char*)ws + half * 32768;
            #pragma unroll
            for (int it = 0; it < 6; ++it) {
                int j = it * 320 + t;
                __builtin_amdgcn_global_load_lds(
                    (const __attribute__((address_space(1))) void*)(src + (size_t)j * 16),
                    (__attribute__((address_space(3))) void*)&ldsB[(it * 320 + wave * 64) * 16],
                    16, 0, 0);
            }
            if (t < 128) {   // tail chunks 1920..2047 (waves 0,1 full)
                int j = 1920 + t;
                __builtin_amdgcn_global_load_lds(
                    (const __attribute__((address_space(1))) void*)(src + (size_t)j * 16),
                    (__attribute__((address_space(3))) void*)&ldsB[(1920 + wave * 64) * 16],
                    16, 0, 0);
            }
        } else {
            // fallback: R9-proven direct gather
            for (int i = t; i < 64 * 32; i += 320) {
                int pl = i & 63;
                int cg = i >> 6;
                const float* src = cm + (size_t)cg * 8 * NPIX + half * 64 + pl;
                u16x8 pk;
                #pragma unroll
                for (int j = 0; j < 8; ++j) pk[j] = f2bf(src[j * NPIX]);
                *reinterpret_cast<u16x8*>(&ldsB[bswz(pl, cg * 16)]) = pk;
            }
        }
        __syncthreads();   // staging visible (drains vmcnt)

        #pragma unroll
        for (int ks = 0; ks < 8; ++ks) {
            const int kb = (ks * 32 + g * 8) * 2;
            #pragma unroll
            for (int m = 0; m < 4; ++m) {
                int pl = m * 16 + lc;         // local pixel row 0..63
                short8 afrag = *reinterpret_cast<short8*>(&ldsB[bswz(pl, kb)]);
                // A = glyph pixels (M), B = cells (N) -> D[pixel][cell]
                acc[half * 4 + m] = __builtin_amdgcn_mfma_f32_16x16x32_bf16(
                    afrag, bpk[ks], acc[half * 4 + m], 0, 0, 0);
            }
        }
        if (half == 0) __syncthreads();   // all waves done reading before restage
    }

    // ---- epilogue: direct register->global, NO LDS, NO barriers ----
    // lane holds D[pixel = m*16 + g*4 + r][cell = cell0+lc]:
    //   y = m*2 + (g>>1), x = (g&1)*4 + r  -> 12 contiguous aligned floats.
    float4* out4 = (float4*)out;
    const size_t basef4 = (size_t)(b * 320 + h * 16) * 480
                        + (size_t)(cell0 + lc) * 6 + (g & 1) * 3;
    const int ybase = g >> 1;

    #pragma unroll
    for (int m = 0; m < 8; ++m) {
        float v[12];
        #pragma unroll
        for (int r = 0; r < 4; ++r) {
            float raw = acc[m][r];
            v[r * 3 + 0] = bg0 + raw * dv0;
            v[r * 3 + 1] = bg1 + raw * dv1;
            v[r * 3 + 2] = bg2 + raw * dv2;
        }
        const size_t o = basef4 + (size_t)(m * 2 + ybase) * 480;
        out4[o + 0] = (float4){v[0], v[1], v[2],  v[3]};
        out4[o + 1] = (float4){v[4], v[5], v[6],  v[7]};
        out4[o + 2] = (float4){v[8], v[9], v[10], v[11]};
    }
}

extern "C" void kernel_launch(void* const* d_in, const int* in_sizes, int n_in,
                              void* d_out, int out_size, void* d_ws, size_t ws_size,
                              hipStream_t stream) {
    (void)in_sizes; (void)n_in; (void)out_size;
    const float* data = (const float*)d_in[0];
    const float* cm   = (const float*)d_in[1];
    float* out        = (float*)d_out;
    const int nblocks = 128 * GRID_H;   // one block per (b, h)
    if (ws_size >= 65536) {
        prep_kernel<<<16, 256, 0, stream>>>(cm, (unsigned short*)d_ws);
        ansi_kernel<true><<<nblocks, 320, 0, stream>>>(
            data, cm, (const unsigned short*)d_ws, out);
    } else {
        ansi_kernel<false><<<nblocks, 320, 0, stream>>>(data, cm, nullptr, out);
    }
}

// Round 14
// 138.572 us; speedup vs baseline: 1.1498x; 1.1498x over previous
//
#include <hip/hip_runtime.h>

#define GRID_H 20
#define GRID_W 80
#define NCH 264
#define K 256
#define NPIX 128   // 16x8 glyph pixels

typedef __attribute__((ext_vector_type(8))) short short8;
typedef __attribute__((ext_vector_type(4))) float f32x4;
typedef __attribute__((ext_vector_type(8))) unsigned short u16x8;

static __device__ __forceinline__ unsigned short f2bf(float f) {
    unsigned int u = __builtin_bit_cast(unsigned int, f);
    u += 0x7FFFu + ((u >> 16) & 1u);   // round-to-nearest-even
    return (unsigned short)(u >> 16);
}

// Swizzled byte offset within a 16KB pixel-quarter (R9/R12-proven swizzle):
// 32 rows (local pixel) x 512B (256 bf16 channels), XOR (pl&7)<<4.
static __device__ __forceinline__ int bswz(int pl, int clbyte) {
    return (pl * 512 + clbyte) ^ ((pl & 7) << 4);
}

// Pack cm (f32 [256 ch][128 px]) -> ws: four 16KB pixel-quarters whose LINEAR
// byte order equals the main kernel's swizzled LDS layout (R12-proven scheme).
__global__ void prep_kernel(const float* __restrict__ cm,
                            unsigned short* __restrict__ ws) {
    int i = blockIdx.x * 256 + threadIdx.x;   // 0..4095 chunks of 16B
    int p  = i & 127;                         // pixel 0..127
    int c8 = i >> 7;                          // channel-group of 8 (0..31)
    int qt = p >> 5, pl = p & 31;             // quarter, local pixel row
    u16x8 pk;
    #pragma unroll
    for (int j = 0; j < 8; ++j) pk[j] = f2bf(cm[(c8 * 8 + j) * NPIX + p]);
    *reinterpret_cast<u16x8*>((char*)ws + qt * 16384 + bswz(pl, c8 * 16)) = pk;
}

// NOTE: plain 1-arg launch_bounds only. The 2-arg form (min waves/EU)
// miscompiled MFMA accumulation in R2/R3/R7.
template <bool USE_WS>
__global__ __launch_bounds__(320) void ansi_kernel(
        const float* __restrict__ data,
        const float* __restrict__ cm,
        const unsigned short* __restrict__ ws,
        float* __restrict__ out) {
    // 16 KB: one PIXEL-quarter of B. + 15 KB S => 31.4 KB -> 5 blocks/CU.
    __shared__ alignas(16) unsigned char ldsB[16384];
    // Wave-PRIVATE epilogue staging (R12-proven): [wave][line][slot][x*3+ch]
    __shared__ alignas(16) float S[5][2][16][24];

    const int blk = blockIdx.x;
    const int b = blk / GRID_H;
    const int h = blk % GRID_H;
    const float* dbase = data + (size_t)(b * GRID_H + h) * GRID_W * NCH;
    const int t = threadIdx.x;
    const int wave = t >> 6;
    const int lane = t & 63;
    const int mrow = lane & 15;     // cell within M-tile (and frag row for B)
    const int g    = lane >> 4;     // k-group
    const int cell0 = wave * 16;

    // ---- fg/bg: lanes 0..15 one cell each, distribute via shfl (proven) ----
    float fb[6] = {0.f, 0.f, 0.f, 0.f, 0.f, 0.f};
    if (lane < 16) {
        const float* q = dbase + (size_t)(cell0 + lane) * NCH + 256;
        float4 a = *reinterpret_cast<const float4*>(q);      // fg_bold, fg.rgb
        float4 c = *reinterpret_cast<const float4*>(q + 4);  // bg_bold, bg.rgb
        float fs = 0.5f * a.x + 0.5f;
        float bs = 0.5f * c.x + 0.5f;
        fb[0] = bs * c.y; fb[1] = bs * c.z; fb[2] = bs * c.w;
        fb[3] = fs * a.y - fb[0];
        fb[4] = fs * a.z - fb[1];
        fb[5] = fs * a.w - fb[2];
    }
    float bgv[4][3], dv[4][3];
    #pragma unroll
    for (int r = 0; r < 4; ++r) {
        int srcl = g * 4 + r;        // source lane = local cell index
        #pragma unroll
        for (int j = 0; j < 3; ++j) {
            bgv[r][j] = __shfl(fb[j], srcl);
            dv[r][j]  = __shfl(fb[3 + j], srcl);
        }
    }

    // ---- load + pack A once (full K=256): 8 x bf16x8 ----
    const float* arow = dbase + (size_t)(cell0 + mrow) * NCH + g * 8;
    short8 apk[8];
    #pragma unroll
    for (int ks = 0; ks < 8; ++ks) {
        float4 a0 = *reinterpret_cast<const float4*>(arow + ks * 32);
        float4 a1 = *reinterpret_cast<const float4*>(arow + ks * 32 + 4);
        u16x8 ap;
        ap[0] = f2bf(a0.x); ap[1] = f2bf(a0.y); ap[2] = f2bf(a0.z); ap[3] = f2bf(a0.w);
        ap[4] = f2bf(a1.x); ap[5] = f2bf(a1.y); ap[6] = f2bf(a1.z); ap[7] = f2bf(a1.w);
        apk[ks] = __builtin_bit_cast(short8, ap);
    }

    f32x4 acc[8];
    #pragma unroll
    for (int n = 0; n < 8; ++n) acc[n] = (f32x4){0.f, 0.f, 0.f, 0.f};

    // ---- GEMM over FOUR pixel-quarters (32 px rows each) ----
    #pragma unroll
    for (int qt = 0; qt < 4; ++qt) {
        if (USE_WS) {
            // async byte-copy: ws linear order == swizzled LDS order (R12)
            const char* src = (const char*)ws + qt * 16384;   // 1024 chunks
            #pragma unroll
            for (int it = 0; it < 3; ++it) {
                int j = it * 320 + t;
                __builtin_amdgcn_global_load_lds(
                    (const __attribute__((address_space(1))) void*)(src + (size_t)j * 16),
                    (__attribute__((address_space(3))) void*)&ldsB[(it * 320 + wave * 64) * 16],
                    16, 0, 0);
            }
            if (t < 64) {   // tail chunks 960..1023 (wave 0 only)
                int j = 960 + t;
                __builtin_amdgcn_global_load_lds(
                    (const __attribute__((address_space(1))) void*)(src + (size_t)j * 16),
                    (__attribute__((address_space(3))) void*)&ldsB[960 * 16],
                    16, 0, 0);
            }
        } else {
            // fallback: R9-proven direct gather (32 rows x 32 ch-groups)
            for (int i = t; i < 32 * 32; i += 320) {
                int pl = i & 31;
                int cg = i >> 5;
                const float* src = cm + (size_t)cg * 8 * NPIX + qt * 32 + pl;
                u16x8 pk;
                #pragma unroll
                for (int j = 0; j < 8; ++j) pk[j] = f2bf(src[j * NPIX]);
                *reinterpret_cast<u16x8*>(&ldsB[bswz(pl, cg * 16)]) = pk;
            }
        }
        __syncthreads();   // staging visible (drains vmcnt)

        #pragma unroll
        for (int ks = 0; ks < 8; ++ks) {
            const int kb = (ks * 32 + g * 8) * 2;
            #pragma unroll
            for (int n = 0; n < 2; ++n) {
                int pl = n * 16 + mrow;       // local pixel row 0..31
                short8 bfrag = *reinterpret_cast<short8*>(&ldsB[bswz(pl, kb)]);
                acc[qt * 2 + n] = __builtin_amdgcn_mfma_f32_16x16x32_bf16(
                    apk[ks], bfrag, acc[qt * 2 + n], 0, 0, 0);
            }
        }
        if (qt < 3) __syncthreads();   // all waves done reading before restage
    }

    // ---- epilogue (R12-proven): wave-private LDS transpose, zero barriers ----
    const int col = lane & 15;
    float4* out4 = (float4*)out;
    const size_t rowf4 = (size_t)(b * 320 + h * 16) * 480 + wave * 96;
    const int line_sel = col >> 3;
    const int x3 = (col & 7) * 3;

    #pragma unroll
    for (int pass = 0; pass < 8; ++pass) {
        #pragma unroll
        for (int r = 0; r < 4; ++r) {
            float raw = acc[pass][r];
            float* o = &S[wave][line_sel][r * 4 + g][x3];
            o[0] = bgv[r][0] + raw * dv[r][0];
            o[1] = bgv[r][1] + raw * dv[r][1];
            o[2] = bgv[r][2] + raw * dv[r][2];
        }
        const float4* Sw = (const float4*)&S[wave][0][0][0];   // 192 float4
        #pragma unroll
        for (int q = 0; q < 3; ++q) {
            int j = q * 64 + lane;            // 0..191
            int line = (j >= 96) ? 1 : 0;
            int rem = j - 96 * line;          // 0..95 = cell*6 + s
            int c = rem / 6;
            int s = rem - 6 * c;
            float4 v = Sw[line * 96 + ((c & 3) * 4 + (c >> 2)) * 6 + s];
            out4[rowf4 + (size_t)(pass * 2 + line) * 480 + rem] = v;
        }
    }
}

extern "C" void kernel_launch(void* const* d_in, const int* in_sizes, int n_in,
                              void* d_out, int out_size, void* d_ws, size_t ws_size,
                              hipStream_t stream) {
    (void)in_sizes; (void)n_in; (void)out_size;
    const float* data = (const float*)d_in[0];
    const float* cm   = (const float*)d_in[1];
    float* out        = (float*)d_out;
    const int nblocks = 128 * GRID_H;   // one block per (b, h)
    if (ws_size >= 65536) {
        prep_kernel<<<16, 256, 0, stream>>>(cm, (unsigned short*)d_ws);
        ansi_kernel<true><<<nblocks, 320, 0, stream>>>(
            data, cm, (const unsigned short*)d_ws, out);
    } else {
        ansi_kernel<false><<<nblocks, 320, 0, stream>>>(data, cm, nullptr, out);
    }
}

// Round 16
// 100.550 us; speedup vs baseline: 1.5846x; 1.3781x over previous
//
#include <hip/hip_runtime.h>

#define GRID_H 20
#define GRID_W 80
#define NCH 264
#define K 256
#define NPIX 128   // 16x8 glyph pixels

typedef __attribute__((ext_vector_type(8))) short short8;
typedef __attribute__((ext_vector_type(4))) float f32x4;
typedef __attribute__((ext_vector_type(8))) unsigned short u16x8;

static __device__ __forceinline__ unsigned short f2bf(float f) {
    unsigned int u = __builtin_bit_cast(unsigned int, f);
    u += 0x7FFFu + ((u >> 16) & 1u);   // round-to-nearest-even
    return (unsigned short)(u >> 16);
}

// Swizzled byte offset within a 32KB pixel-half (R9/R12-proven layout):
// 64 rows (local pixel) x 512B (256 bf16 channels), XOR (pl&7)<<4.
static __device__ __forceinline__ int bswz(int pl, int clbyte) {
    return (pl * 512 + clbyte) ^ ((pl & 7) << 4);
}

// Pack cm (f32 [256 ch][128 px]) -> ws: two 32KB pixel-halves whose LINEAR
// byte order equals the main kernel's swizzled LDS layout (R12-proven).
__global__ void prep_kernel(const float* __restrict__ cm,
                            unsigned short* __restrict__ ws) {
    int i = blockIdx.x * 256 + threadIdx.x;   // 0..4095 chunks of 16B
    int p  = i & 127;                         // pixel 0..127
    int c8 = i >> 7;                          // channel-group of 8 (0..31)
    int hf = p >> 6, pl = p & 63;
    u16x8 pk;
    #pragma unroll
    for (int j = 0; j < 8; ++j) pk[j] = f2bf(cm[(c8 * 8 + j) * NPIX + p]);
    *reinterpret_cast<u16x8*>((char*)ws + hf * 32768 + bswz(pl, c8 * 16)) = pk;
}

// NOTE: plain 1-arg launch_bounds only. The 2-arg form (min waves/EU)
// miscompiled MFMA accumulation in R2/R3/R7.
template <bool USE_WS>
__global__ __launch_bounds__(320) void ansi_kernel(
        const float* __restrict__ data,
        const float* __restrict__ cm,
        const unsigned short* __restrict__ ws,
        float* __restrict__ out) {
    // 32 KB: one PIXEL-half of B (R9/R12-proven). Staged per half.
    __shared__ alignas(16) unsigned char ldsB[32768];
    // Wave-PRIVATE epilogue staging (R9-proven): [wave][line][slot][x*3+ch]
    __shared__ alignas(16) float S[5][2][16][24];   // 15 KB; total 47 KB

    const int blk = blockIdx.x;
    const int b = blk / GRID_H;
    const int h = blk % GRID_H;
    const float* dbase = data + (size_t)(b * GRID_H + h) * GRID_W * NCH;
    const int t = threadIdx.x;
    const int wave = t >> 6;
    const int lane = t & 63;
    const int mrow = lane & 15;     // cell within M-tile
    const int g    = lane >> 4;     // k-group
    const int cell0 = wave * 16;

    // ---- fg/bg: lanes 0..15 one cell each, distribute via shfl ----
    float fb[6] = {0.f, 0.f, 0.f, 0.f, 0.f, 0.f};
    if (lane < 16) {
        const float* q = dbase + (size_t)(cell0 + lane) * NCH + 256;
        float4 a = *reinterpret_cast<const float4*>(q);      // fg_bold, fg.rgb
        float4 c = *reinterpret_cast<const float4*>(q + 4);  // bg_bold, bg.rgb
        float fs = 0.5f * a.x + 0.5f;
        float bs = 0.5f * c.x + 0.5f;
        fb[0] = bs * c.y; fb[1] = bs * c.z; fb[2] = bs * c.w;
        fb[3] = fs * a.y - fb[0];
        fb[4] = fs * a.z - fb[1];
        fb[5] = fs * a.w - fb[2];
    }
    float bgv[4][3], dv[4][3];
    #pragma unroll
    for (int r = 0; r < 4; ++r) {
        int srcl = g * 4 + r;        // source lane = local cell index
        #pragma unroll
        for (int j = 0; j < 3; ++j) {
            bgv[r][j] = __shfl(fb[j], srcl);
            dv[r][j]  = __shfl(fb[3 + j], srcl);
        }
    }

    // ---- load + pack A once (full K=256): 8 x bf16x8 ----
    const float* arow = dbase + (size_t)(cell0 + mrow) * NCH + g * 8;
    short8 apk[8];
    #pragma unroll
    for (int ks = 0; ks < 8; ++ks) {
        float4 a0 = *reinterpret_cast<const float4*>(arow + ks * 32);
        float4 a1 = *reinterpret_cast<const float4*>(arow + ks * 32 + 4);
        u16x8 ap;
        ap[0] = f2bf(a0.x); ap[1] = f2bf(a0.y); ap[2] = f2bf(a0.z); ap[3] = f2bf(a0.w);
        ap[4] = f2bf(a1.x); ap[5] = f2bf(a1.y); ap[6] = f2bf(a1.z); ap[7] = f2bf(a1.w);
        apk[ks] = __builtin_bit_cast(short8, ap);
    }

    f32x4 acc[8];
    #pragma unroll
    for (int n = 0; n < 8; ++n) acc[n] = (f32x4){0.f, 0.f, 0.f, 0.f};

    // ---- GEMM over two pixel-halves; 3 barriers total (R12 structure) ----
    #pragma unroll
    for (int half = 0; half < 2; ++half) {
        if (USE_WS) {
            // async byte-copy: ws linear order == swizzled LDS order (R12)
            const char* src = (const char*)ws + half * 32768;
            #pragma unroll
            for (int it = 0; it < 6; ++it) {
                int j = it * 320 + t;
                __builtin_amdgcn_global_load_lds(
                    (const __attribute__((address_space(1))) void*)(src + (size_t)j * 16),
                    (__attribute__((address_space(3))) void*)&ldsB[(it * 320 + wave * 64) * 16],
                    16, 0, 0);
            }
            if (t < 128) {   // tail chunks 1920..2047 (waves 0,1 full)
                int j = 1920 + t;
                __builtin_amdgcn_global_load_lds(
                    (const __attribute__((address_space(1))) void*)(src + (size_t)j * 16),
                    (__attribute__((address_space(3))) void*)&ldsB[(1920 + wave * 64) * 16],
                    16, 0, 0);
            }
        } else {
            // fallback: R9-proven direct gather
            for (int i = t; i < 64 * 32; i += 320) {
                int pl = i & 63;
                int cg = i >> 6;
                const float* src = cm + (size_t)cg * 8 * NPIX + half * 64 + pl;
                u16x8 pk;
                #pragma unroll
                for (int j = 0; j < 8; ++j) pk[j] = f2bf(src[j * NPIX]);
                *reinterpret_cast<u16x8*>(&ldsB[bswz(pl, cg * 16)]) = pk;
            }
        }
        __syncthreads();   // staging visible (drains vmcnt)

        #pragma unroll
        for (int ks = 0; ks < 8; ++ks) {
            const int kbase = ks * 32 + g * 8;
            #pragma unroll
            for (int n = 0; n < 4; ++n) {
                int pl = n * 16 + mrow;       // local pixel row 0..63
                short8 bfrag = *reinterpret_cast<short8*>(&ldsB[bswz(pl, kbase * 2)]);
                acc[half * 4 + n] = __builtin_amdgcn_mfma_f32_16x16x32_bf16(
                    apk[ks], bfrag, acc[half * 4 + n], 0, 0, 0);
            }
        }
        if (half == 0) __syncthreads();   // all waves done reading before restage
    }

    // ---- epilogue (R12 + NT stores): wave-private LDS transpose ----
    const int col = lane & 15;
    f32x4* out4 = (f32x4*)out;          // ext_vector type for NT builtin
    const size_t rowf4 = (size_t)(b * 320 + h * 16) * 480 + wave * 96;
    const int line_sel = col >> 3;
    const int x3 = (col & 7) * 3;

    #pragma unroll
    for (int pass = 0; pass < 8; ++pass) {
        #pragma unroll
        for (int r = 0; r < 4; ++r) {
            float raw = acc[pass][r];
            float* o = &S[wave][line_sel][r * 4 + g][x3];
            o[0] = bgv[r][0] + raw * dv[r][0];
            o[1] = bgv[r][1] + raw * dv[r][1];
            o[2] = bgv[r][2] + raw * dv[r][2];
        }
        const f32x4* Sw = (const f32x4*)&S[wave][0][0][0];   // 192 f32x4
        #pragma unroll
        for (int q = 0; q < 3; ++q) {
            int j = q * 64 + lane;            // 0..191
            int line = (j >= 96) ? 1 : 0;
            int rem = j - 96 * line;          // 0..95 = cell*6 + s
            int c = rem / 6;
            int s = rem - 6 * c;
            f32x4 v = Sw[line * 96 + ((c & 3) * 4 + (c >> 2)) * 6 + s];
            // NT store: output is write-once, never re-read during timing —
            // keep it out of L2/L3 so `data` stays cache-resident.
            __builtin_nontemporal_store(
                v, &out4[rowf4 + (size_t)(pass * 2 + line) * 480 + rem]);
        }
    }
}

extern "C" void kernel_launch(void* const* d_in, const int* in_sizes, int n_in,
                              void* d_out, int out_size, void* d_ws, size_t ws_size,
                              hipStream_t stream) {
    (void)in_sizes; (void)n_in; (void)out_size;
    const float* data = (const float*)d_in[0];
    const float* cm   = (const float*)d_in[1];
    float* out        = (float*)d_out;
    const int nblocks = 128 * GRID_H;   // one block per (b, h)
    if (ws_size >= 65536) {
        prep_kernel<<<16, 256, 0, stream>>>(cm, (unsigned short*)d_ws);
        ansi_kernel<true><<<nblocks, 320, 0, stream>>>(
            data, cm, (const unsigned short*)d_ws, out);
    } else {
        ansi_kernel<false><<<nblocks, 320, 0, stream>>>(data, cm, nullptr, out);
    }
}